// Round 9
// baseline (414.198 us; speedup 1.0000x reference)
//
#include <hip/hip_runtime.h>
#include <hip/hip_bf16.h>

#define FEAT 256
#define HID 128
#define CLASSES 32
#define LAYERS 3

typedef float f4 __attribute__((ext_vector_type(4)));
typedef float f2 __attribute__((ext_vector_type(2)));
typedef __attribute__((ext_vector_type(8))) short short8;
typedef __attribute__((ext_vector_type(4))) float f32x4;
typedef unsigned int u32;
typedef __attribute__((ext_vector_type(4))) unsigned int u32x4;

// fp32 -> bf16 RNE
__device__ __forceinline__ unsigned short bf16_rne(float v) {
    unsigned u = __float_as_uint(v);
    return (unsigned short)((u + 0x7FFF + ((u >> 16) & 1)) >> 16);
}
// pack two fp32 -> u32 of 2 bf16 (elem0 low, elem1 high)
__device__ __forceinline__ u32 bf16x2_rne(float a, float b) {
    return (u32)bf16_rne(a) | ((u32)bf16_rne(b) << 16);
}

// ---------------- CSR build ----------------

__global__ void count_kernel(const int* __restrict__ dst, int* __restrict__ counts, int E) {
    int e = blockIdx.x * blockDim.x + threadIdx.x;
    if (e < E) atomicAdd(&counts[dst[e]], 1);
}

__global__ void partial_kernel(const int* __restrict__ counts, int* __restrict__ partials, int N) {
    int t = threadIdx.x;
    int i = blockIdx.x * 256 + t;
    int v = (i < N) ? counts[i] : 0;
#pragma unroll
    for (int off = 32; off >= 1; off >>= 1) v += __shfl_down(v, off, 64);
    __shared__ int ws[4];
    if ((t & 63) == 0) ws[t >> 6] = v;
    __syncthreads();
    if (t == 0) partials[blockIdx.x] = ws[0] + ws[1] + ws[2] + ws[3];
}

__global__ void scan_partials_kernel(const int* __restrict__ partials, int* __restrict__ poff, int NB) {
    int t = threadIdx.x, lane = t & 63, w = t >> 6;
    int v = (t < NB) ? partials[t] : 0;
    int x = v;
#pragma unroll
    for (int off = 1; off < 64; off <<= 1) {
        int y = __shfl_up(x, off, 64);
        if (lane >= off) x += y;
    }
    __shared__ int ws[4];
    if (lane == 63) ws[w] = x;
    __syncthreads();
    int woff = 0;
    for (int k = 0; k < w; ++k) woff += ws[k];
    if (t < NB) poff[t] = woff + x - v;
}

__global__ void scan_final_kernel(const int* __restrict__ counts, const int* __restrict__ poff,
                                  int* __restrict__ row_off, int* __restrict__ cursor, int N) {
    int t = threadIdx.x, lane = t & 63, w = t >> 6;
    int i = blockIdx.x * 256 + t;
    int v = (i < N) ? counts[i] : 0;
    int x = v;
#pragma unroll
    for (int off = 1; off < 64; off <<= 1) {
        int y = __shfl_up(x, off, 64);
        if (lane >= off) x += y;
    }
    __shared__ int ws[4];
    if (lane == 63) ws[w] = x;
    __syncthreads();
    int woff = 0;
    for (int k = 0; k < w; ++k) woff += ws[k];
    int excl = poff[blockIdx.x] + woff + x - v;
    if (i < N) {
        row_off[i] = excl;
        cursor[i] = excl;
        if (i == N - 1) row_off[N] = excl + v;
    }
}

__global__ void fill_kernel(const int* __restrict__ src, const int* __restrict__ dst,
                            int* __restrict__ cursor, int* __restrict__ csr_src, int E) {
    int e = blockIdx.x * blockDim.x + threadIdx.x;
    if (e < E) {
        int pos = atomicAdd(&cursor[dst[e]], 1);
        csr_src[pos] = src[e];
    }
}

// ---------------- weight prep (merged): transposed single-bf16 tables ----------------
// we: [n=128][k=256] from emb_w[k][n]
// wl: 3 x [n=128][k=256]; k<128 -> rel_w[l][k][n], k>=128 -> root_w[l][k-128][n]
// wp: [c=64][k=128]; c<32 -> head_w[k][c], else head_w[128+k][c-32]
__global__ void prep_kernel(const float* __restrict__ emb_w, const float* __restrict__ rel_w,
                            const float* __restrict__ root_w, const float* __restrict__ head_w,
                            unsigned short* __restrict__ we, unsigned short* __restrict__ wl,
                            unsigned short* __restrict__ wp) {
    int idx = blockIdx.x * 256 + threadIdx.x;
    if (idx < 128 * 256) {
        int n = idx >> 8, k = idx & 255;
        we[n * 256 + k] = bf16_rne(emb_w[k * 128 + n]);
    } else if (idx < 4 * 128 * 256) {
        int i = idx - 128 * 256;
        int l = i >> 15;
        int r = i & 32767;
        int n = r >> 8, k = r & 255;
        float v = (k < 128) ? rel_w[l * 16384 + k * 128 + n] : root_w[l * 16384 + (k - 128) * 128 + n];
        wl[i] = bf16_rne(v);
    } else if (idx < 4 * 128 * 256 + 64 * 128) {
        int i = idx - 4 * 128 * 256;
        int c = i >> 7, k = i & 127;
        float v = (c < 32) ? head_w[k * 32 + c] : head_w[(128 + k) * 32 + (c - 32)];
        wp[c * 128 + k] = bf16_rne(v);
    }
}

// ---------------- MFMA bf16 GEMM, register-resident B, zero LDS / zero barriers ----------------
// out[M x NCOL] = act( concatK(A0|A1)[M x KTOT] @ W[KTOT x NCOL] + bias )
// W pre-transposed single bf16: W[n][k] (n-major, stride KTOT).
// AFMT: 0 = A fp32 (cvt to bf16 in-register), 1 = A bf16 (direct fragment load).
// PACKOUT: epilogue writes bf16 (ushort) vs fp32.
// Block = 256 threads = 4 waves covering 64 rows; wave w owns column quarter
// [w*NCOL/4, +NCOL/4). Each wave loads its whole B panel ONCE into registers
// (16KB = 64 VGPR for NCOL=128; register layout IS the MFMA B-fragment layout,
// same W[col][k] addressing the LDS path staged). Then 4x16-row A tiles are
// streamed with next-tile prefetch. No LDS, no __syncthreads: all latency hides
// under 64 independent MFMA chains + ~3 blocks/CU TLP (grid = ceil(M/64)).
template <int NCOL, int KTOT, bool RELU, int AFMT, bool PACKOUT>
__global__ __launch_bounds__(256) void gemm_mfma(
    const void* __restrict__ A0v, int lda0,
    const void* __restrict__ A1v, int lda1, int K0,
    const unsigned short* __restrict__ W,
    const float* __restrict__ bias, void* __restrict__ outv, int M) {
    constexpr int NCHUNK = KTOT / 32;
    constexpr int WCOL = NCOL / 4;     // 32 (NCOL=128) or 16 (NCOL=64)
    constexpr int NCT = WCOL / 16;     // 2 or 1

    int wv = threadIdx.x >> 6;
    int lane = threadIdx.x & 63;
    int m16 = lane & 15;
    int quad = lane >> 4;
    int colbase = wv * WCOL;
    int rowblk = blockIdx.x * 64;

    // B panel -> registers (per (ct,kc): lane m16 = col, quad*8 = k-offset)
    short8 Bf[NCT][NCHUNK];
#pragma unroll
    for (int ct = 0; ct < NCT; ++ct)
#pragma unroll
        for (int kc = 0; kc < NCHUNK; ++kc)
            Bf[ct][kc] = *(const short8*)(const void*)(W + (size_t)(colbase + ct * 16 + m16) * KTOT + kc * 32 + quad * 8);

    float bcol[NCT];
#pragma unroll
    for (int ct = 0; ct < NCT; ++ct) bcol[ct] = bias ? bias[colbase + ct * 16 + m16] : 0.f;

    f32x4 acc[4][NCT] = {};

    auto aaddr = [&](int t, int kc) -> const void* {
        int r = rowblk + t * 16 + m16;
        r = (r < M) ? r : (M - 1);  // clamp reads; stores guarded below
        bool second = (kc * 32 >= K0);
        int lda = second ? lda1 : lda0;
        int kofs = kc * 32 - (second ? K0 : 0);
        if (AFMT == 0)
            return (const float*)(second ? A1v : A0v) + (size_t)r * lda + kofs + quad * 8;
        else
            return (const unsigned short*)(second ? A1v : A0v) + (size_t)r * lda + kofs + quad * 8;
    };

    if (AFMT == 1) {
        // bf16 A: direct fragment loads, next-tile prefetch
        short8 Ac[NCHUNK], An[NCHUNK];
#pragma unroll
        for (int kc = 0; kc < NCHUNK; ++kc) Ac[kc] = *(const short8*)aaddr(0, kc);
#pragma unroll
        for (int t = 0; t < 4; ++t) {
            if (t + 1 < 4) {
#pragma unroll
                for (int kc = 0; kc < NCHUNK; ++kc) An[kc] = *(const short8*)aaddr(t + 1, kc);
            }
#pragma unroll
            for (int kc = 0; kc < NCHUNK; ++kc)
#pragma unroll
                for (int ct = 0; ct < NCT; ++ct)
                    acc[t][ct] = __builtin_amdgcn_mfma_f32_16x16x32_bf16(Ac[kc], Bf[ct][kc], acc[t][ct], 0, 0, 0);
            if (t + 1 < 4) {
#pragma unroll
                for (int kc = 0; kc < NCHUNK; ++kc) Ac[kc] = An[kc];
            }
        }
    } else {
        // fp32 A (embed): per tile, batch-issue raw loads, convert, MFMA
#pragma unroll
        for (int t = 0; t < 4; ++t) {
            u32x4 raw[NCHUNK][2];
#pragma unroll
            for (int kc = 0; kc < NCHUNK; ++kc) {
                const u32x4* p = (const u32x4*)aaddr(t, kc);
                raw[kc][0] = p[0];
                raw[kc][1] = p[1];
            }
#pragma unroll
            for (int kc = 0; kc < NCHUNK; ++kc) {
                union { u32x4 u[2]; float f[8]; } cv;
                cv.u[0] = raw[kc][0];
                cv.u[1] = raw[kc][1];
                short8 Af;
#pragma unroll
                for (int j = 0; j < 8; ++j) Af[j] = (short)bf16_rne(cv.f[j]);
#pragma unroll
                for (int ct = 0; ct < NCT; ++ct)
                    acc[t][ct] = __builtin_amdgcn_mfma_f32_16x16x32_bf16(Af, Bf[ct][kc], acc[t][ct], 0, 0, 0);
            }
        }
    }

    // epilogue: C/D layout col = lane&15, row = quad*4 + reg
#pragma unroll
    for (int t = 0; t < 4; ++t) {
#pragma unroll
        for (int r = 0; r < 4; ++r) {
            int row = rowblk + t * 16 + quad * 4 + r;
            if (row < M) {
#pragma unroll
                for (int ct = 0; ct < NCT; ++ct) {
                    float v = acc[t][ct][r] + bcol[ct];
                    if (RELU) v = fmaxf(v, 0.f);
                    size_t idx = (size_t)row * NCOL + colbase + ct * 16 + m16;
                    if (PACKOUT) ((unsigned short*)outv)[idx] = bf16_rne(v);
                    else ((float*)outv)[idx] = v;
                }
            }
        }
    }
}

// ---------------- aggregation (CSR gather-sum, bf16 rows, 4-wide pipelined MLP) ----------------
// x rows are bf16 [N][128] (u32 = 2 elems/lane, 64 lanes = full row, 256B/gather).
// fp32 accumulate; epilogue packs back to bf16.
__global__ void aggregate_kernel(const u32* __restrict__ x, const int* __restrict__ row_off,
                                 const int* __restrict__ csr, u32* __restrict__ agg, int N) {
    int gw = (blockIdx.x * 256 + threadIdx.x) >> 6;
    int lane = threadIdx.x & 63;
    if (gw >= N) return;
    int beg = row_off[gw], end = row_off[gw + 1];

    f2 a0 = (f2)0.f, a1 = (f2)0.f, a2 = (f2)0.f, a3 = (f2)0.f;

    auto unp = [](u32 u) -> f2 {
        f2 r;
        r[0] = __uint_as_float(u << 16);
        r[1] = __uint_as_float(u & 0xFFFF0000u);
        return r;
    };

    int nfull = (end - beg) >> 2;
    int j = beg;
    if (nfull > 0) {
        int s0 = csr[j], s1 = csr[j + 1], s2 = csr[j + 2], s3 = csr[j + 3];
        for (int b = 1; b < nfull; ++b) {
            u32 v0 = x[(size_t)s0 * 64 + lane];
            u32 v1 = x[(size_t)s1 * 64 + lane];
            u32 v2 = x[(size_t)s2 * 64 + lane];
            u32 v3 = x[(size_t)s3 * 64 + lane];
            int jn = j + 4;
            s0 = csr[jn]; s1 = csr[jn + 1]; s2 = csr[jn + 2]; s3 = csr[jn + 3];
            a0 += unp(v0); a1 += unp(v1); a2 += unp(v2); a3 += unp(v3);
            j = jn;
        }
        u32 v0 = x[(size_t)s0 * 64 + lane];
        u32 v1 = x[(size_t)s1 * 64 + lane];
        u32 v2 = x[(size_t)s2 * 64 + lane];
        u32 v3 = x[(size_t)s3 * 64 + lane];
        a0 += unp(v0); a1 += unp(v1); a2 += unp(v2); a3 += unp(v3);
        j += 4;
    }

    int rem = end - j;
    if (rem > 0) {
        int e1 = end - 1;
        int t0 = csr[j];
        int t1 = csr[min(j + 1, e1)];
        int t2 = csr[min(j + 2, e1)];
        u32 w0 = x[(size_t)t0 * 64 + lane];
        u32 w1 = x[(size_t)t1 * 64 + lane];
        u32 w2 = x[(size_t)t2 * 64 + lane];
        a0 += unp(w0);
        if (rem > 1) a1 += unp(w1);
        if (rem > 2) a2 += unp(w2);
    }

    f2 a = (a0 + a2) + (a1 + a3);
    agg[(size_t)gw * 64 + lane] = bf16x2_rne(a[0], a[1]);
}

// ---------------- edge head ----------------
// out[e][c] = pspd[src[e]][c] + pspd[dst[e]][32+c] + head_b[c]
__global__ void edge_out_kernel(const int* __restrict__ src, const int* __restrict__ dst,
                                const float* __restrict__ pspd, const float* __restrict__ head_b,
                                float* __restrict__ out, int E) {
    int idx = blockIdx.x * blockDim.x + threadIdx.x;
    int e = idx >> 3;
    int c4 = (idx & 7) * 4;
    if (e >= E) return;
    int s = src[e], d = dst[e];
    f4 a = *(const f4*)&pspd[(size_t)s * 64 + c4];
    f4 b = *(const f4*)&pspd[(size_t)d * 64 + 32 + c4];
    f4 hb = *(const f4*)&head_b[c4];
    f4 o = a + b + hb;
    *(f4*)&out[(size_t)e * CLASSES + c4] = o;
}

// ---------------- launcher ----------------

extern "C" void kernel_launch(void* const* d_in, const int* in_sizes, int n_in,
                              void* d_out, int out_size, void* d_ws, size_t ws_size,
                              hipStream_t stream) {
    const float* feat   = (const float*)d_in[0];
    const int*   eidx   = (const int*)d_in[1];
    const float* emb_w  = (const float*)d_in[2];
    const float* emb_b  = (const float*)d_in[3];
    const float* rel_w  = (const float*)d_in[4];
    const float* rel_b  = (const float*)d_in[5];
    const float* root_w = (const float*)d_in[6];
    const float* head_w = (const float*)d_in[7];
    const float* head_b = (const float*)d_in[8];
    float* out = (float*)d_out;

    int N = in_sizes[0] / FEAT;
    int E = in_sizes[1] / 2;
    const int* src = eidx;
    const int* dst = eidx + E;

    // workspace layout: bf16 activation buffers (as u32 regions), pspd fp32 aliases agg,
    // then ints, then single-bf16 weight tables
    u32* xA  = (u32*)d_ws;                  // N*64 u32 = N*128 bf16
    u32* xB  = xA + (size_t)N * 64;         // N*64 u32
    u32* agg = xB + (size_t)N * 64;         // N*64 u32 (pspd aliases: N*64 fp32 = same bytes)
    int* counts   = (int*)(agg + (size_t)N * 64);   // N
    int* row_off  = counts + N;                     // N+1
    int* cursor   = row_off + (N + 1);              // N
    int* csr_src  = cursor + N;                     // E
    int* partials = csr_src + E;                    // 256
    int* poff     = partials + 256;                 // 256
    int* iend     = poff + 256;
    // pad int region to 16B boundary
    size_t ioff = (size_t)(iend - (int*)d_ws);
    ioff = (ioff + 3) & ~(size_t)3;
    unsigned short* we = (unsigned short*)((int*)d_ws + ioff);  // 128*256
    unsigned short* wl = we + 128 * 256;                        // 3*128*256
    unsigned short* wp = wl + 3 * 128 * 256;                    // 64*128

    int NB = (N + 255) / 256;

    hipMemsetAsync(counts, 0, (size_t)N * sizeof(int), stream);
    count_kernel<<<(E + 255) / 256, 256, 0, stream>>>(dst, counts, E);
    partial_kernel<<<NB, 256, 0, stream>>>(counts, partials, N);
    scan_partials_kernel<<<1, 256, 0, stream>>>(partials, poff, NB);
    scan_final_kernel<<<NB, 256, 0, stream>>>(counts, poff, row_off, cursor, N);
    fill_kernel<<<(E + 255) / 256, 256, 0, stream>>>(src, dst, cursor, csr_src, E);

    prep_kernel<<<(4 * 128 * 256 + 64 * 128 + 255) / 256, 256, 0, stream>>>(
        emb_w, rel_w, root_w, head_w, we, wl, wp);

    int grid = (N + 63) / 64;
    // embed: xA = bf16(relu(feat @ emb_w + emb_b)); A fp32
    gemm_mfma<HID, FEAT, true, 0, true><<<grid, 256, 0, stream>>>(
        feat, FEAT, nullptr, 0, FEAT, we, emb_b, xA, N);

    const u32* xin = xA;
    u32* xout = xB;
    for (int l = 0; l < LAYERS; ++l) {
        aggregate_kernel<<<(N * 64 + 255) / 256, 256, 0, stream>>>(xin, row_off, csr_src, agg, N);
        gemm_mfma<HID, 2 * HID, true, 1, true><<<grid, 256, 0, stream>>>(
            agg, HID, xin, HID, HID,
            wl + (size_t)l * 128 * 256, rel_b + (size_t)l * HID, xout, N);
        u32* tmp = (u32*)xin; xin = xout; xout = tmp;
    }

    // pspd = x @ Wpp (no bias/relu), fp32 out; aliases agg
    float* pspd = (float*)agg;
    gemm_mfma<64, HID, false, 1, false><<<grid, 256, 0, stream>>>(
        xin, HID, nullptr, 0, HID, wp, nullptr, pspd, N);

    edge_out_kernel<<<((size_t)E * 8 + 255) / 256, 256, 0, stream>>>(src, dst, pspd, head_b, out, E);
}

// Round 11
// 343.485 us; speedup vs baseline: 1.2059x; 1.2059x over previous
//
#include <hip/hip_runtime.h>
#include <hip/hip_bf16.h>

#define FEAT 256
#define HID 128
#define CLASSES 32
#define LAYERS 3

typedef float f4 __attribute__((ext_vector_type(4)));
typedef float f2 __attribute__((ext_vector_type(2)));
typedef __attribute__((ext_vector_type(8))) short short8;
typedef __attribute__((ext_vector_type(4))) float f32x4;
typedef unsigned int u32;
typedef __attribute__((ext_vector_type(4))) unsigned int u32x4;

// fp32 -> bf16 RNE
__device__ __forceinline__ unsigned short bf16_rne(float v) {
    unsigned u = __float_as_uint(v);
    return (unsigned short)((u + 0x7FFF + ((u >> 16) & 1)) >> 16);
}
// pack two fp32 -> u32 of 2 bf16 (elem0 low, elem1 high)
__device__ __forceinline__ u32 bf16x2_rne(float a, float b) {
    return (u32)bf16_rne(a) | ((u32)bf16_rne(b) << 16);
}

// ---------------- CSR build ----------------

__global__ void count_kernel(const int* __restrict__ dst, int* __restrict__ counts, int E) {
    int e = blockIdx.x * blockDim.x + threadIdx.x;
    if (e < E) atomicAdd(&counts[dst[e]], 1);
}

__global__ void partial_kernel(const int* __restrict__ counts, int* __restrict__ partials, int N) {
    int t = threadIdx.x;
    int i = blockIdx.x * 256 + t;
    int v = (i < N) ? counts[i] : 0;
#pragma unroll
    for (int off = 32; off >= 1; off >>= 1) v += __shfl_down(v, off, 64);
    __shared__ int ws[4];
    if ((t & 63) == 0) ws[t >> 6] = v;
    __syncthreads();
    if (t == 0) partials[blockIdx.x] = ws[0] + ws[1] + ws[2] + ws[3];
}

__global__ void scan_partials_kernel(const int* __restrict__ partials, int* __restrict__ poff, int NB) {
    int t = threadIdx.x, lane = t & 63, w = t >> 6;
    int v = (t < NB) ? partials[t] : 0;
    int x = v;
#pragma unroll
    for (int off = 1; off < 64; off <<= 1) {
        int y = __shfl_up(x, off, 64);
        if (lane >= off) x += y;
    }
    __shared__ int ws[4];
    if (lane == 63) ws[w] = x;
    __syncthreads();
    int woff = 0;
    for (int k = 0; k < w; ++k) woff += ws[k];
    if (t < NB) poff[t] = woff + x - v;
}

__global__ void scan_final_kernel(const int* __restrict__ counts, const int* __restrict__ poff,
                                  int* __restrict__ row_off, int* __restrict__ cursor, int N) {
    int t = threadIdx.x, lane = t & 63, w = t >> 6;
    int i = blockIdx.x * 256 + t;
    int v = (i < N) ? counts[i] : 0;
    int x = v;
#pragma unroll
    for (int off = 1; off < 64; off <<= 1) {
        int y = __shfl_up(x, off, 64);
        if (lane >= off) x += y;
    }
    __shared__ int ws[4];
    if (lane == 63) ws[w] = x;
    __syncthreads();
    int woff = 0;
    for (int k = 0; k < w; ++k) woff += ws[k];
    int excl = poff[blockIdx.x] + woff + x - v;
    if (i < N) {
        row_off[i] = excl;
        cursor[i] = excl;
        if (i == N - 1) row_off[N] = excl + v;
    }
}

__global__ void fill_kernel(const int* __restrict__ src, const int* __restrict__ dst,
                            int* __restrict__ cursor, int* __restrict__ csr_src, int E) {
    int e = blockIdx.x * blockDim.x + threadIdx.x;
    if (e < E) {
        int pos = atomicAdd(&cursor[dst[e]], 1);
        csr_src[pos] = src[e];
    }
}

// ---------------- weight prep (merged): transposed single-bf16 tables ----------------
// we: [n=128][k=256] from emb_w[k][n]
// wl: 3 x [n=128][k=256]; k<128 -> rel_w[l][k][n], k>=128 -> root_w[l][k-128][n]
// wp: [c=64][k=128]; c<32 -> head_w[k][c], else head_w[128+k][c-32]
__global__ void prep_kernel(const float* __restrict__ emb_w, const float* __restrict__ rel_w,
                            const float* __restrict__ root_w, const float* __restrict__ head_w,
                            unsigned short* __restrict__ we, unsigned short* __restrict__ wl,
                            unsigned short* __restrict__ wp) {
    int idx = blockIdx.x * 256 + threadIdx.x;
    if (idx < 128 * 256) {
        int n = idx >> 8, k = idx & 255;
        we[n * 256 + k] = bf16_rne(emb_w[k * 128 + n]);
    } else if (idx < 4 * 128 * 256) {
        int i = idx - 128 * 256;
        int l = i >> 15;
        int r = i & 32767;
        int n = r >> 8, k = r & 255;
        float v = (k < 128) ? rel_w[l * 16384 + k * 128 + n] : root_w[l * 16384 + (k - 128) * 128 + n];
        wl[i] = bf16_rne(v);
    } else if (idx < 4 * 128 * 256 + 64 * 128) {
        int i = idx - 4 * 128 * 256;
        int c = i >> 7, k = i & 127;
        float v = (c < 32) ? head_w[k * 32 + c] : head_w[(128 + k) * 32 + (c - 32)];
        wp[c * 128 + k] = bf16_rne(v);
    }
}

// ---------------- MFMA bf16 GEMM, double-buffered LDS B, 1 barrier/chunk (round-8 structure) ----------------
// out[M x NCOL] = act( concatK(A0|A1)[M x KTOT] @ W[KTOT x NCOL] + bias )
// W pre-transposed single bf16: W[n][k] (n-major, stride KTOT).
// AFMT: 0 = A fp32 (cvt to bf16 in-register), 1 = A bf16 (direct fragment load).
// PACKOUT: epilogue writes bf16 (ushort) vs fp32.
// Block = 256 threads = 4 waves; wave w owns rows [blk*128 + w*32, +32) x all NCOL.
// Pipeline per chunk kc (K=32): ds_write chunk kc+1 into buf[p^1] (loads issued 2
// chunks ahead), issue B loads kc+2 + A loads kc+1, build A frags, ds_read buf[p]
// + 1 MFMA per (ct,rt), ONE barrier.
template <int NCOL, int KTOT, bool RELU, int AFMT, bool PACKOUT>
__global__ __launch_bounds__(256) void gemm_mfma(
    const void* __restrict__ A0v, int lda0,
    const void* __restrict__ A1v, int lda1, int K0,
    const unsigned short* __restrict__ W,
    const float* __restrict__ bias, void* __restrict__ outv, int M) {
    constexpr int NCHUNK = KTOT / 32;
    constexpr int NCT = NCOL / 16;     // 8 (NCOL=128) or 4 (NCOL=64)
    constexpr int CB = NCOL * 64;      // LDS bytes per chunk buffer (single bf16)
    constexpr int NI = NCOL / 16;      // stage instrs per chunk (per block)
    constexpr int NIW = NI / 4;        // per wave: 2 or 1
    constexpr int ASZ = (AFMT == 0) ? 2 : 1;  // u32x4 regs per A frag

    __shared__ unsigned char lds[2][CB];

    int wv = threadIdx.x >> 6;
    int lane = threadIdx.x & 63;
    int m16 = lane & 15;
    int quad = lane >> 4;
    int rowbase = blockIdx.x * 128 + wv * 32;

    int arow[2];
#pragma unroll
    for (int rt = 0; rt < 2; ++rt) {
        int r = rowbase + rt * 16 + m16;
        arow[rt] = (r < M) ? r : (M - 1);  // clamp reads; stores guarded below
    }

    // stage instr i: cols [i*16,+16); lane covers col i*16+(lane>>2), quarter lane&3 (8 bf16 = 16B)
    auto g_src = [&](int i, int kc) -> const unsigned short* {
        return W + (size_t)(i * 16 + (lane >> 2)) * KTOT + kc * 32 + (lane & 3) * 8;
    };
    auto dstoff = [&](int i) -> int { return i * 1024 + lane * 16; };
    auto aptr = [&](int kc, int rt) -> const void* {
        bool second = (kc * 32 >= K0);
        int lda = second ? lda1 : lda0;
        int kofs = kc * 32 - (second ? K0 : 0);
        if (AFMT == 0)
            return (const float*)(second ? A1v : A0v) + (size_t)arow[rt] * lda + kofs + quad * 8;
        else
            return (const unsigned short*)(second ? A1v : A0v) + (size_t)arow[rt] * lda + kofs + quad * 8;
    };

    f32x4 acc[2][NCT] = {};
    float bcol[NCT];
#pragma unroll
    for (int ct = 0; ct < NCT; ++ct) bcol[ct] = bias ? bias[ct * 16 + m16] : 0.f;

    // ---- prologue ----
    u32x4 stg[NIW];
#pragma unroll
    for (int ii = 0; ii < NIW; ++ii) stg[ii] = *(const u32x4*)(const void*)g_src(wv * NIW + ii, 0);
    u32x4 ra[2][ASZ];
#pragma unroll
    for (int rt = 0; rt < 2; ++rt) {
        const u32x4* p = (const u32x4*)aptr(0, rt);
        ra[rt][0] = p[0];
        if (AFMT == 0) ra[rt][1] = p[1];
    }
    // commit chunk0 into buf0 (waits on chunk0 loads)
#pragma unroll
    for (int ii = 0; ii < NIW; ++ii) *(u32x4*)(void*)(&lds[0][dstoff(wv * NIW + ii)]) = stg[ii];
    // issue chunk1 B loads (written at kc=0)
    if (NCHUNK > 1) {
#pragma unroll
        for (int ii = 0; ii < NIW; ++ii) stg[ii] = *(const u32x4*)(const void*)g_src(wv * NIW + ii, 1);
    }
    __syncthreads();  // buf0 visible

#pragma unroll
    for (int kc = 0; kc < NCHUNK; ++kc) {
        int p = kc & 1;

        // 1. write chunk kc+1 into buf[p^1]; issue chunk kc+2 B loads
        if (kc + 1 < NCHUNK) {
#pragma unroll
            for (int ii = 0; ii < NIW; ++ii) *(u32x4*)(void*)(&lds[p ^ 1][dstoff(wv * NIW + ii)]) = stg[ii];
            if (kc + 2 < NCHUNK) {
#pragma unroll
                for (int ii = 0; ii < NIW; ++ii) stg[ii] = *(const u32x4*)(const void*)g_src(wv * NIW + ii, kc + 2);
            }
        }

        // 2. issue next chunk's A loads -- fly during MFMA
        u32x4 na[2][ASZ];
        if (kc + 1 < NCHUNK) {
#pragma unroll
            for (int rt = 0; rt < 2; ++rt) {
                const u32x4* pn = (const u32x4*)aptr(kc + 1, rt);
                na[rt][0] = pn[0];
                if (AFMT == 0) na[rt][1] = pn[1];
            }
        }

        // 3. build A fragments (bf16 direct, or fp32 cvt for embed)
        short8 Ah[2];
#pragma unroll
        for (int rt = 0; rt < 2; ++rt) {
            if (AFMT == 0) {
                union { u32x4 u[2]; float f[8]; } cv;
                cv.u[0] = ra[rt][0];
                cv.u[1] = ra[rt][1];
#pragma unroll
                for (int j = 0; j < 8; ++j) Ah[rt][j] = (short)bf16_rne(cv.f[j]);
            } else {
                union { u32x4 u; short8 s; } cv;
                cv.u = ra[rt][0];
                Ah[rt] = cv.s;
            }
        }

        // 4. compute from buf[p]: per ct, 1 ds_read_b128 + 2 MFMAs
#pragma unroll
        for (int ct = 0; ct < NCT; ++ct) {
            const unsigned char* ph = &lds[p][(ct * 16 + m16) * 64 + quad * 16];
            short8 Bh = *(const short8*)(const void*)ph;
#pragma unroll
            for (int rt = 0; rt < 2; ++rt)
                acc[rt][ct] = __builtin_amdgcn_mfma_f32_16x16x32_bf16(Ah[rt], Bh, acc[rt][ct], 0, 0, 0);
        }

        if (kc + 1 < NCHUNK) {
#pragma unroll
            for (int rt = 0; rt < 2; ++rt) {
                ra[rt][0] = na[rt][0];
                if (AFMT == 0) ra[rt][1] = na[rt][1];
            }
        }

        __syncthreads();  // reads of buf[p] done; writes to buf[p^1] visible
    }

    // epilogue: C/D layout col = lane&15, row = quad*4 + reg
#pragma unroll
    for (int rt = 0; rt < 2; ++rt) {
#pragma unroll
        for (int r = 0; r < 4; ++r) {
            int row = rowbase + rt * 16 + quad * 4 + r;
            if (row < M) {
#pragma unroll
                for (int ct = 0; ct < NCT; ++ct) {
                    float v = acc[rt][ct][r] + bcol[ct];
                    if (RELU) v = fmaxf(v, 0.f);
                    size_t idx = (size_t)row * NCOL + ct * 16 + m16;
                    if (PACKOUT) ((unsigned short*)outv)[idx] = bf16_rne(v);
                    else ((float*)outv)[idx] = v;
                }
            }
        }
    }
}

// ---------------- aggregation (CSR gather-sum, bf16 rows, 8-wide masked MLP) ----------------
// x rows are bf16 [N][128] (u32 = 2 elems/lane, 64 lanes = full row, 256B/gather).
// 8 independent gathers in flight per wave (avg degree 12 -> ~1.5 iterations);
// clamped addresses + uniform-branch masked accumulate; index prefetch overlaps
// the gathers. fp32 accumulate; epilogue packs back to bf16.
__global__ void aggregate_kernel(const u32* __restrict__ x, const int* __restrict__ row_off,
                                 const int* __restrict__ csr, u32* __restrict__ agg, int N) {
    int gw = (blockIdx.x * 256 + threadIdx.x) >> 6;
    int lane = threadIdx.x & 63;
    if (gw >= N) return;
    int beg = row_off[gw], end = row_off[gw + 1];

    if (end <= beg) {
        agg[(size_t)gw * 64 + lane] = 0u;
        return;
    }

    auto unp = [](u32 u) -> f2 {
        f2 r;
        r[0] = __uint_as_float(u << 16);
        r[1] = __uint_as_float(u & 0xFFFF0000u);
        return r;
    };

    f2 a[8];
#pragma unroll
    for (int k = 0; k < 8; ++k) a[k] = (f2)0.f;

    int e1 = end - 1;
    int s[8];
#pragma unroll
    for (int k = 0; k < 8; ++k) s[k] = csr[min(beg + k, e1)];

    int j = beg;
    while (j < end) {
        // 8 independent row gathers (clamped indices; masked below)
        u32 v[8];
#pragma unroll
        for (int k = 0; k < 8; ++k) v[k] = x[(size_t)s[k] * 64 + lane];

        // prefetch next batch's indices while gathers are in flight
        int jn = j + 8;
        if (jn < end) {
#pragma unroll
            for (int k = 0; k < 8; ++k) s[k] = csr[min(jn + k, e1)];
        }

        // masked accumulate (j uniform per wave -> scalar branches)
#pragma unroll
        for (int k = 0; k < 8; ++k)
            if (j + k < end) a[k] += unp(v[k]);

        j = jn;
    }

    f2 r = ((a[0] + a[4]) + (a[1] + a[5])) + ((a[2] + a[6]) + (a[3] + a[7]));
    agg[(size_t)gw * 64 + lane] = bf16x2_rne(r[0], r[1]);
}

// ---------------- edge head ----------------
// out[e][c] = pspd[src[e]][c] + pspd[dst[e]][32+c] + head_b[c]
__global__ void edge_out_kernel(const int* __restrict__ src, const int* __restrict__ dst,
                                const float* __restrict__ pspd, const float* __restrict__ head_b,
                                float* __restrict__ out, int E) {
    int idx = blockIdx.x * blockDim.x + threadIdx.x;
    int e = idx >> 3;
    int c4 = (idx & 7) * 4;
    if (e >= E) return;
    int s = src[e], d = dst[e];
    f4 a = *(const f4*)&pspd[(size_t)s * 64 + c4];
    f4 b = *(const f4*)&pspd[(size_t)d * 64 + 32 + c4];
    f4 hb = *(const f4*)&head_b[c4];
    f4 o = a + b + hb;
    *(f4*)&out[(size_t)e * CLASSES + c4] = o;
}

// ---------------- launcher ----------------

extern "C" void kernel_launch(void* const* d_in, const int* in_sizes, int n_in,
                              void* d_out, int out_size, void* d_ws, size_t ws_size,
                              hipStream_t stream) {
    const float* feat   = (const float*)d_in[0];
    const int*   eidx   = (const int*)d_in[1];
    const float* emb_w  = (const float*)d_in[2];
    const float* emb_b  = (const float*)d_in[3];
    const float* rel_w  = (const float*)d_in[4];
    const float* rel_b  = (const float*)d_in[5];
    const float* root_w = (const float*)d_in[6];
    const float* head_w = (const float*)d_in[7];
    const float* head_b = (const float*)d_in[8];
    float* out = (float*)d_out;

    int N = in_sizes[0] / FEAT;
    int E = in_sizes[1] / 2;
    const int* src = eidx;
    const int* dst = eidx + E;

    // workspace layout: bf16 activation buffers (as u32 regions), pspd fp32 aliases agg,
    // then ints, then single-bf16 weight tables
    u32* xA  = (u32*)d_ws;                  // N*64 u32 = N*128 bf16
    u32* xB  = xA + (size_t)N * 64;         // N*64 u32
    u32* agg = xB + (size_t)N * 64;         // N*64 u32 (pspd aliases: N*64 fp32 = same bytes)
    int* counts   = (int*)(agg + (size_t)N * 64);   // N
    int* row_off  = counts + N;                     // N+1
    int* cursor   = row_off + (N + 1);              // N
    int* csr_src  = cursor + N;                     // E
    int* partials = csr_src + E;                    // 256
    int* poff     = partials + 256;                 // 256
    int* iend     = poff + 256;
    // pad int region to 16B boundary
    size_t ioff = (size_t)(iend - (int*)d_ws);
    ioff = (ioff + 3) & ~(size_t)3;
    unsigned short* we = (unsigned short*)((int*)d_ws + ioff);  // 128*256
    unsigned short* wl = we + 128 * 256;                        // 3*128*256
    unsigned short* wp = wl + 3 * 128 * 256;                    // 64*128

    int NB = (N + 255) / 256;

    hipMemsetAsync(counts, 0, (size_t)N * sizeof(int), stream);
    count_kernel<<<(E + 255) / 256, 256, 0, stream>>>(dst, counts, E);
    partial_kernel<<<NB, 256, 0, stream>>>(counts, partials, N);
    scan_partials_kernel<<<1, 256, 0, stream>>>(partials, poff, NB);
    scan_final_kernel<<<NB, 256, 0, stream>>>(counts, poff, row_off, cursor, N);
    fill_kernel<<<(E + 255) / 256, 256, 0, stream>>>(src, dst, cursor, csr_src, E);

    prep_kernel<<<(4 * 128 * 256 + 64 * 128 + 255) / 256, 256, 0, stream>>>(
        emb_w, rel_w, root_w, head_w, we, wl, wp);

    int grid = (N + 127) / 128;
    // embed: xA = bf16(relu(feat @ emb_w + emb_b)); A fp32
    gemm_mfma<HID, FEAT, true, 0, true><<<grid, 256, 0, stream>>>(
        feat, FEAT, nullptr, 0, FEAT, we, emb_b, xA, N);

    const u32* xin = xA;
    u32* xout = xB;
    for (int l = 0; l < LAYERS; ++l) {
        aggregate_kernel<<<(N * 64 + 255) / 256, 256, 0, stream>>>(xin, row_off, csr_src, agg, N);
        gemm_mfma<HID, 2 * HID, true, 1, true><<<grid, 256, 0, stream>>>(
            agg, HID, xin, HID, HID,
            wl + (size_t)l * 128 * 256, rel_b + (size_t)l * HID, xout, N);
        u32* tmp = (u32*)xin; xin = xout; xout = tmp;
    }

    // pspd = x @ Wpp (no bias/relu), fp32 out; aliases agg
    float* pspd = (float*)agg;
    gemm_mfma<64, HID, false, 1, false><<<grid, 256, 0, stream>>>(
        xin, HID, nullptr, 0, HID, wp, nullptr, pspd, N);

    edge_out_kernel<<<((size_t)E * 8 + 255) / 256, 256, 0, stream>>>(src, dst, pspd, head_b, out, E);
}